// Round 1
// 150.987 us; speedup vs baseline: 1.0615x; 1.0615x over previous
//
#include <hip/hip_runtime.h>

// LDPC neural BP decoder, MI355X. Round 11.
// Theory: LDS pipe ~60% busy (63K base + 66K conflict cyc/CU) is the primary
// resource; the 40% gap to it was (a) dynamic-index scratch for vm/vmp state
// (rule #20: unroll-1 + vm0[k] -> private array -> L3-bounced scratch; VGPR=64
// too low for 36-float state, WRITE_SIZE +8MiB anomaly) and (b) 10 barriers.
// This round:
//  - fused iteration: gather -> check -> nv -> tanh(nv) -> write next t-buffer
//  - double-buffered t-table (135168 B LDS, 1 block/CU) -> 5 barriers not 10
//  - phase loop FULLY unrolled, sched_barrier(0) fences between k-regions cap
//    pressure (prevents the R6 spill mode); state v2f arrays live in VGPRs
//  - wllr hoisted to registers (kills per-iter in0/in1 loads)
//  - w_res pair packed into offs slots 10/11 (one fewer stream)
//  - gather = off + per-iter base v_add: preserves the known 8.2cyc/b64
//    conflict profile (16B-interleave rejected: 8 bank-pairs -> +60% conflict)

#define NN    8448
#define MAXNB 10
#define TPB   1024
#define MAXK  9       // ceil(8448/1024)
#define ITERS 5
#define TBL_BYTES  (NN * 8)                 // 67584: one t-buffer, v2f per node
#define LDS_BYTES  (2 * TBL_BYTES)          // 135168: double-buffered
#define OFFS_INTS  12                       // 10 byte-offs + {wr0,wr1} bits
#define OFFS_BYTES ((size_t)NN * OFFS_INTS * sizeof(int))   // 405504
#define WS_NEEDED  OFFS_BYTES

typedef float v2f __attribute__((ext_vector_type(2)));

__global__ __launch_bounds__(256)
void prep_kernel(const int* __restrict__ cidx, const float* __restrict__ w_res,
                 int* __restrict__ offs)
{
    int n = blockIdx.x * 256 + threadIdx.x;
    if (n < NN) {
        #pragma unroll
        for (int j = 0; j < MAXNB; ++j)
            offs[n * OFFS_INTS + j] = cidx[n * MAXNB + j] * 8;  // byte off of v2f
        offs[n * OFFS_INTS + 10] = __float_as_int(w_res[n]);
        offs[n * OFFS_INTS + 11] = __float_as_int(w_res[NN + n]);
    }
}

// t = tanh(clip(0.5*v, +-9.9)) = 1 - 2/(exp(clip(v,+-19.8))+1), both rows,
// shared reciprocal: r = rcp(A*B); 1/A = r*B; 1/B = r*A.
__device__ __forceinline__ v2f tanh_half(v2f v)
{
    v2f y = __builtin_elementwise_min(
                __builtin_elementwise_max(v, (v2f)(-19.8f)), (v2f)(19.8f));
    v2f e;
    e.x = __expf(y.x);
    e.y = __expf(y.y);
    v2f ab = e + 1.0f;                               // {A,B}
    float r = __builtin_amdgcn_rcpf(ab.x * ab.y);
    v2f ba = ab.yx;                                  // {B,A}
    v2f inv = ba * r;                                // {1/A,1/B}
    return 1.0f - 2.0f * inv;                        // contracts to pk_fma
}

template<bool USE_OFF>
__global__ __launch_bounds__(TPB)
void ldpc_decode_kernel(const float* __restrict__ input_llr,
                        const float* __restrict__ w_ch,
                        const float* __restrict__ w_res,   // [2][NN]
                        const int*   __restrict__ cidx,    // [NN][10]
                        const int*   __restrict__ offs,    // [NN][12]
                        float* __restrict__ out)
{
    extern __shared__ char smem[];
    const int tid  = threadIdx.x;
    const int row0 = blockIdx.x * 2;
    const float* __restrict__ in0 = input_llr + (size_t)row0 * NN;
    const float* __restrict__ in1 = in0 + NN;
    float* __restrict__ out0 = out + (size_t)row0 * NN;
    float* __restrict__ out1 = out0 + NN;

    // persistent state, ALL statically indexed -> VGPRs (54 regs)
    v2f wllr[MAXK], vm[MAXK], vmp[MAXK];

    // prologue: init state, write t(vm) into buffer 0
    #pragma unroll
    for (int k = 0; k < MAXK; ++k) {
        int n = tid + k * TPB;
        wllr[k] = (v2f)(0.0f);
        vmp[k]  = (v2f)(0.0f);
        if (k < MAXK - 1 || n < NN) {
            float wc = w_ch[n];
            v2f x;
            x.x = in0[n];
            x.y = in1[n];
            wllr[k] = x * wc;
        }
        vm[k] = wllr[k];
        if (k < MAXK - 1 || n < NN) {
            v2f t = tanh_half(vm[k]);
            *(v2f*)(smem + (size_t)n * 8) = t;       // buffer 0
        }
    }
    __syncthreads();

    #pragma unroll
    for (int it = 0; it < ITERS; ++it) {
        const int rbase = (it & 1) ? TBL_BYTES : 0;  // compile-time per it
        const int wbase = (it & 1) ? 0 : TBL_BYTES;
        #pragma unroll
        for (int k = 0; k < MAXK; ++k) {
            int n = tid + k * TPB;
            if (k < MAXK - 1 || n < NN) {
                int o0, o1, o2, o3, o4, o5, o6, o7, o8, o9;
                float wr0, wr1;
                if (USE_OFF) {
                    const int4* op = (const int4*)(offs + n * OFFS_INTS);
                    int4 oA = op[0];                 // rows are 48B, 16-aligned
                    int4 oB = op[1];
                    int4 oC = op[2];
                    o0 = oA.x; o1 = oA.y; o2 = oA.z; o3 = oA.w;
                    o4 = oB.x; o5 = oB.y; o6 = oB.z; o7 = oB.w;
                    o8 = oC.x; o9 = oC.y;
                    wr0 = __int_as_float(oC.z);
                    wr1 = __int_as_float(oC.w);
                } else {
                    const int2* ip = (const int2*)(cidx + n * MAXNB);
                    int2 i0 = ip[0], i1 = ip[1], i2 = ip[2], i3 = ip[3], i4 = ip[4];
                    o0 = i0.x << 3; o1 = i0.y << 3;
                    o2 = i1.x << 3; o3 = i1.y << 3;
                    o4 = i2.x << 3; o5 = i2.y << 3;
                    o6 = i3.x << 3; o7 = i3.y << 3;
                    o8 = i4.x << 3; o9 = i4.y << 3;
                    wr0 = w_res[n];
                    wr1 = w_res[NN + n];
                }
                const char* __restrict__ rb = smem + rbase;
                v2f g0 = *(const v2f*)(rb + o0);
                v2f g1 = *(const v2f*)(rb + o1);
                v2f g2 = *(const v2f*)(rb + o2);
                v2f g3 = *(const v2f*)(rb + o3);
                v2f g4 = *(const v2f*)(rb + o4);
                v2f g5 = *(const v2f*)(rb + o5);
                v2f g6 = *(const v2f*)(rb + o6);
                v2f g7 = *(const v2f*)(rb + o7);
                v2f g8 = *(const v2f*)(rb + o8);
                v2f g9 = *(const v2f*)(rb + o9);
                // pk product tree (same association as R10)
                v2f m01 = (g0 * g1) * (g2 * g3);
                v2f m23 = (g4 * g5) * (g6 * g7);
                v2f pr  = (m01 * m23) * (g8 * g9);
                pr = __builtin_elementwise_min(
                         __builtin_elementwise_max(pr, (v2f)(-0.999999f)),
                         (v2f)(0.999999f));
                v2f num = 1.0f + pr;
                v2f den = 1.0f - pr;
                v2f ln, ld;
                ln.x = __log2f(num.x);
                ln.y = __log2f(num.y);
                ld.x = __log2f(den.x);
                ld.y = __log2f(den.y);
                v2f check = (ln - ld) * 0.69314718f;
                v2f res = vm[k] * wr0 + vmp[k] * wr1;     // pk_fma
                v2f nv  = (wllr[k] + check) + res;
                vmp[k] = vm[k];
                vm[k]  = nv;
                if (it < ITERS - 1) {
                    v2f t = tanh_half(nv);                // fused next phase-1
                    *(v2f*)(smem + wbase + (size_t)n * 8) = t;
                }
            }
            // fence: cap per-region register pressure (prevents R6 spill mode)
            __builtin_amdgcn_sched_barrier(0);
        }
        if (it < ITERS - 1) __syncthreads();              // one barrier per iter
    }

    // epilogue: sigmoid(vm + input)
    #pragma unroll
    for (int k = 0; k < MAXK; ++k) {
        int n = tid + k * TPB;
        if (k < MAXK - 1 || n < NN) {
            float x0 = vm[k].x + in0[n];
            float x1 = vm[k].y + in1[n];
            out0[n] = __fdividef(1.0f, 1.0f + __expf(-x0));
            out1[n] = __fdividef(1.0f, 1.0f + __expf(-x1));
        }
    }
}

extern "C" void kernel_launch(void* const* d_in, const int* in_sizes, int n_in,
                              void* d_out, int out_size, void* d_ws, size_t ws_size,
                              hipStream_t stream) {
    const float* input_llr = (const float*)d_in[0];
    const float* w_ch      = (const float*)d_in[1];
    const float* w_res     = (const float*)d_in[2];
    const int*   cidx      = (const int*)d_in[3];
    // d_in[4] (var_index_tensor) is unused by the reference
    float* out = (float*)d_out;
    int batch = in_sizes[0] / NN;
    const bool use_off = (ws_size >= WS_NEEDED) && (d_ws != nullptr);

    hipFuncSetAttribute((const void*)ldpc_decode_kernel<true>,
                        hipFuncAttributeMaxDynamicSharedMemorySize, LDS_BYTES);
    hipFuncSetAttribute((const void*)ldpc_decode_kernel<false>,
                        hipFuncAttributeMaxDynamicSharedMemorySize, LDS_BYTES);

    if (use_off) {
        int* offs = (int*)d_ws;
        hipLaunchKernelGGL(prep_kernel, dim3((NN + 255) / 256), dim3(256), 0,
                           stream, cidx, w_res, offs);
        hipLaunchKernelGGL(ldpc_decode_kernel<true>, dim3(batch / 2), dim3(TPB),
                           LDS_BYTES, stream, input_llr, w_ch, w_res, cidx,
                           offs, out);
    } else {
        hipLaunchKernelGGL(ldpc_decode_kernel<false>, dim3(batch / 2), dim3(TPB),
                           LDS_BYTES, stream, input_llr, w_ch, w_res, cidx,
                           nullptr, out);
    }
}